// Round 7
// baseline (440.829 us; speedup 1.0000x reference)
//
#include <hip/hip_runtime.h>

#define D 128

typedef __attribute__((ext_vector_type(8))) short bf16x8;
typedef __attribute__((ext_vector_type(4))) float f32x4;

// ---------------- bf16 helpers (RTN-even) ----------------
__device__ __forceinline__ unsigned short f2bf(float f) {
  union { float f; unsigned int u; } c; c.f = f;
  unsigned int u = c.u;
  unsigned int r = (u + 0x7fffu + ((u >> 16) & 1u)) >> 16;
  return (unsigned short)r;
}
__device__ __forceinline__ float bf2f(unsigned short h) {
  return __uint_as_float(((unsigned int)h) << 16);
}
__device__ __forceinline__ float bf_lo(unsigned int w) {
  return __uint_as_float(w << 16);
}
__device__ __forceinline__ float bf_hi(unsigned int w) {
  return __uint_as_float(w & 0xffff0000u);
}
__device__ __forceinline__ void split2(float a, float b, unsigned int& hi, unsigned int& lo) {
  unsigned short ha = f2bf(a), hb = f2bf(b);
  unsigned short la = f2bf(a - bf2f(ha)), lb = f2bf(b - bf2f(hb));
  hi = (unsigned int)ha | ((unsigned int)hb << 16);
  lo = (unsigned int)la | ((unsigned int)lb << 16);
}

// A-fragment layout: Af[((t*12 + s)*64 + (row&15) + 16*((k&31)>>3))*8 + (k&7)]
__device__ __forceinline__ void frag_write(unsigned short* __restrict__ Afh,
                                           unsigned short* __restrict__ Afl,
                                           int t, int r, int k, float a, float b) {
  unsigned int hh, hl;
  split2(a, b, hh, hl);
  int s = k >> 5, ksub = (k & 31) >> 3, e = k & 7;
  size_t addr = ((size_t)(t * 12 + s) * 64 + r + 16 * ksub) * 8 + e;
  *(unsigned int*)&Afh[addr] = hh;
  *(unsigned int*)&Afl[addr] = hl;
}

// ---------------- CSR build ----------------

__global__ void hist2_k(const int* __restrict__ dst1, int* __restrict__ c1, int E1,
                        const int* __restrict__ dst2, int* __restrict__ c2, int E2) {
  int e = blockIdx.x * blockDim.x + threadIdx.x;
  if (e < E1) atomicAdd(&c1[dst1[e]], 1);
  int e2 = e - E1;
  if (e2 >= 0 && e2 < E2) atomicAdd(&c2[dst2[e2]], 1);
}

__device__ void exscan_dev(int* cnt_cursor, int* rp, int n) {
  __shared__ int wsum[16];
  __shared__ int carry_s;
  const int tid = threadIdx.x;
  const int lane = tid & 63, wid = tid >> 6;
  if (tid == 0) carry_s = 0;
  __syncthreads();
  for (int base = 0; base < n; base += 1024) {
    int idx = base + tid;
    int v = (idx < n) ? cnt_cursor[idx] : 0;
    int s = v;
#pragma unroll
    for (int ofs = 1; ofs < 64; ofs <<= 1) {
      int t = __shfl_up(s, ofs);
      if (lane >= ofs) s += t;
    }
    if (lane == 63) wsum[wid] = s;
    __syncthreads();
    if (wid == 0) {
      int ws = (lane < 16) ? wsum[lane] : 0;
#pragma unroll
      for (int ofs = 1; ofs < 16; ofs <<= 1) {
        int t = __shfl_up(ws, ofs);
        if (lane >= ofs) ws += t;
      }
      if (lane < 16) wsum[lane] = ws;
    }
    __syncthreads();
    int pre = (wid > 0) ? wsum[wid - 1] : 0;
    int carry = carry_s;
    int ex = carry + pre + s - v;
    if (idx < n) { rp[idx] = ex; cnt_cursor[idx] = ex; }
    __syncthreads();
    if (tid == 1023) carry_s = carry + wsum[15];
    __syncthreads();
  }
  if (tid == 0) rp[n] = carry_s;
}

__global__ void exscan2_k(int* c1, int* r1, int* c2, int* r2, int n) {
  if (blockIdx.x == 0) exscan_dev(c1, r1, n);
  else exscan_dev(c2, r2, n);
}

__global__ void fill2_k(const int* __restrict__ src1, const int* __restrict__ dst1,
                        int* __restrict__ cur1, int* __restrict__ out1, int E1,
                        const int* __restrict__ src2, const int* __restrict__ dst2,
                        int* __restrict__ cur2, int* __restrict__ out2, int E2) {
  int e = blockIdx.x * blockDim.x + threadIdx.x;
  if (e < E1) {
    int pos = atomicAdd(&cur1[dst1[e]], 1);
    out1[pos] = src1[e];
  }
  int e2 = e - E1;
  if (e2 >= 0 && e2 < E2) {
    int pos = atomicAdd(&cur2[dst2[e2]], 1);
    out2[pos] = src2[e2];
  }
}

// ---------------- weight precompute ----------------
__global__ __launch_bounds__(256) void pre1_k(
    const float* __restrict__ Wq, const float* __restrict__ Wk,
    const float* __restrict__ W0, const float* __restrict__ W1,
    const float* __restrict__ Wv,
    float* __restrict__ M, float* __restrict__ Wc) {
  int bx = blockIdx.x;
  if (bx < 64) {
    int r = bx * 2 + (threadIdx.x >> 7);
    int c = threadIdx.x & 127;
    float acc = 0.f;
    for (int d = 0; d < D; ++d) acc += Wq[r * D + d] * Wk[c * D + d];
    M[r * D + c] = acc;
  } else {
    int idx = (bx - 64) * 256 + threadIdx.x;
    int r = idx >> 7, c = idx & 127;
    float v;
    if (r < 128) v = W0[r * D + c];
    else if (r < 256) v = W1[(r - 128) * D + c];
    else v = -Wv[(r - 256) * D + c];
    Wc[idx] = v;
  }
}

__global__ __launch_bounds__(256) void pre2_k(const float* __restrict__ Wc,
                                              const float* __restrict__ M,
                                              float* __restrict__ WM) {
  int idx = blockIdx.x * blockDim.x + threadIdx.x;
  if (idx >= 384 * D) return;
  int r = idx >> 7, c = idx & 127;
  float acc = 0.f;
  for (int k = 0; k < D; ++k) acc += Wc[r * D + k] * M[k * D + c];
  WM[idx] = acc;
}

// pre3: B fragments. Bf: [ntg 16][s 12][64][8] from [Wc|WM]; Mf: [ntg 8][s 4][64][8] from M.
__global__ __launch_bounds__(256) void pre3_k(
    const float* __restrict__ Wc, const float* __restrict__ WM,
    const float* __restrict__ M,
    unsigned short* __restrict__ Bfh, unsigned short* __restrict__ Bfl,
    unsigned short* __restrict__ Mfh, unsigned short* __restrict__ Mfl) {
  int idx = blockIdx.x * blockDim.x + threadIdx.x;
  if (idx < 16 * 12 * 512) {
    int e = idx & 7, l = (idx >> 3) & 63;
    int s = (idx >> 9) % 12, ntg = idx / (12 * 512);
    int n = ntg * 16 + (l & 15);
    int k = s * 32 + (l >> 4) * 8 + e;
    float v = (n < 128) ? Wc[k * D + n] : WM[k * D + (n - 128)];
    unsigned short h = f2bf(v);
    Bfh[idx] = h;
    Bfl[idx] = f2bf(v - bf2f(h));
  } else {
    int i2 = idx - 16 * 12 * 512;
    if (i2 >= 8 * 4 * 512) return;
    int e = i2 & 7, l = (i2 >> 3) & 63;
    int s = (i2 >> 9) & 3, ntg = i2 / (4 * 512);
    int n = ntg * 16 + (l & 15);
    int k = s * 32 + (l >> 4) * 8 + e;
    float v = M[k * D + n];
    unsigned short h = f2bf(v);
    Mfh[i2] = h;
    Mfl[i2] = f2bf(v - bf2f(h));
  }
}

// x -> A fragments cols 0..127 AND compact bf16 copy Hb
__global__ __launch_bounds__(256) void cvt_k(const float* __restrict__ x,
                                             unsigned short* __restrict__ Afh,
                                             unsigned short* __restrict__ Afl,
                                             unsigned short* __restrict__ Hb, int n) {
  int idx = blockIdx.x * blockDim.x + threadIdx.x;   // n = N*64
  if (idx >= n) return;
  int row = idx >> 6, f = (idx & 63) * 2;
  float2 v = *(const float2*)&x[row * D + f];
  frag_write(Afh, Afl, row >> 4, row & 15, f, v.x, v.y);
  unsigned int p = (unsigned int)f2bf(v.x) | ((unsigned int)f2bf(v.y) << 16);
  *(unsigned int*)&Hb[(size_t)row * D + f] = p;
}

// ---------------- gather/aggregate: TWO waves per node (edge-range split) ----------------
__device__ __forceinline__ float wave_reduce_sum(float v) {
  v += __shfl_xor(v, 32);
  v += __shfl_xor(v, 16);
  v += __shfl_xor(v, 8);
  v += __shfl_xor(v, 4);
  v += __shfl_xor(v, 2);
  v += __shfl_xor(v, 1);
  return v;
}

__global__ __launch_bounds__(256) void agg_k(
    const float* __restrict__ h, int ldh,
    const float* __restrict__ qt,                  // ld 256
    const unsigned short* __restrict__ Hb,         // N x 128 bf16 (gather source)
    const int* __restrict__ rp1, const int* __restrict__ s1,
    const int* __restrict__ rp2, const int* __restrict__ s2,
    unsigned short* __restrict__ Afh, unsigned short* __restrict__ Afl, int N) {
  __shared__ float part[2][2][128];                // [node-in-block][a1/a2][col]
  const int wid = threadIdx.x >> 6;
  const int l = threadIdx.x & 63;
  const int nl = wid >> 1;                         // node within block (0,1)
  const int half = wid & 1;                        // edge-range half
  int node = blockIdx.x * 2 + nl;
  if (node >= N) return;                           // pairs exit together; barrier OK
  const int i = __builtin_amdgcn_readfirstlane(node);
  const int f = 2 * l;

  float2 q = *(const float2*)&qt[(size_t)i * 256 + f];
  float2 a1 = make_float2(0.f, 0.f);
  float2 a2 = make_float2(0.f, 0.f);

  // ---- TAGConv neighbor sum (this wave's half of CSR1) ----
  {
    int lo = __builtin_amdgcn_readfirstlane(rp1[i]);
    int hi = __builtin_amdgcn_readfirstlane(rp1[i + 1]);
    int mid = lo + ((hi - lo) >> 1);
    int e = half ? mid : lo;
    int end = half ? hi : mid;
    for (; e + 8 <= end; e += 8) {
      unsigned int w[8];
#pragma unroll
      for (int u = 0; u < 8; ++u) {
        int j = s1[e + u];
        w[u] = *(const unsigned int*)&Hb[(size_t)j * D + f];
      }
#pragma unroll
      for (int u = 0; u < 8; ++u) { a1.x += bf_lo(w[u]); a1.y += bf_hi(w[u]); }
    }
    for (; e < end; ++e) {
      int j = s1[e];
      unsigned int w = *(const unsigned int*)&Hb[(size_t)j * D + f];
      a1.x += bf_lo(w); a1.y += bf_hi(w);
    }
  }

  // ---- attention aggregate (this wave's half of CSR2) ----
  {
    int lo = __builtin_amdgcn_readfirstlane(rp2[i]);
    int hi = __builtin_amdgcn_readfirstlane(rp2[i + 1]);
    int mid = lo + ((hi - lo) >> 1);
    int e = half ? mid : lo;
    int end = half ? hi : mid;
    for (; e + 4 <= end; e += 4) {
      float2 v[4]; float p[4];
#pragma unroll
      for (int u = 0; u < 4; ++u) {
        int j = s2[e + u];
        unsigned int w = *(const unsigned int*)&Hb[(size_t)j * D + f];
        v[u] = make_float2(bf_lo(w), bf_hi(w));
      }
#pragma unroll
      for (int u = 0; u < 4; ++u) p[u] = q.x * v[u].x + q.y * v[u].y;
#pragma unroll
      for (int ofs = 32; ofs >= 1; ofs >>= 1) {
#pragma unroll
        for (int u = 0; u < 4; ++u) p[u] += __shfl_xor(p[u], ofs);
      }
#pragma unroll
      for (int u = 0; u < 4; ++u) {
        a2.x += p[u] * v[u].x; a2.y += p[u] * v[u].y;
      }
    }
    for (; e < end; ++e) {
      int j = s2[e];
      unsigned int w = *(const unsigned int*)&Hb[(size_t)j * D + f];
      float2 v = make_float2(bf_lo(w), bf_hi(w));
      float p = wave_reduce_sum(q.x * v.x + q.y * v.y);
      a2.x += p * v.x; a2.y += p * v.y;
    }
  }

  // ---- combine halves via LDS; half 0 writes fragments ----
  if (half) {
    part[nl][0][f] = a1.x; part[nl][0][f + 1] = a1.y;
    part[nl][1][f] = a2.x; part[nl][1][f + 1] = a2.y;
  }
  __syncthreads();
  if (!half) {
    a1.x += part[nl][0][f]; a1.y += part[nl][0][f + 1];
    a2.x += part[nl][1][f]; a2.y += part[nl][1][f + 1];
    float2 hrow = *(const float2*)&h[(size_t)i * ldh + f];
    const int t = i >> 4, r = i & 15;
    frag_write(Afh, Afl, t, r, f, hrow.x, hrow.y);
    frag_write(Afh, Afl, t, r, 128 + f, a1.x, a1.y);
    frag_write(Afh, Afl, t, r, 256 + f, a2.x, a2.y);
  }
}

// ---------------- fragment-layout split-bf16 MFMA GEMM ----------------
// Block 256 = 4 waves (2 row-halves x 2 col-halves). Wave: 64 rows (4 tiles) x 64 cols (4 ntiles).
__global__ __launch_bounds__(256) void gemm_mfma(
    const unsigned short* __restrict__ Afh, const unsigned short* __restrict__ Afl,
    int ksteps,
    const unsigned short* __restrict__ Bfh, const unsigned short* __restrict__ Bfl,
    int outcol0, float* __restrict__ C, int ldc,
    unsigned short* __restrict__ Hb,            // optional bf16 copy (main gemm, cols<128)
    int N, int ntiles) {
  const int w = threadIdx.x >> 6, l = threadIdx.x & 63;
  const int wr = w & 1, wc = w >> 1;
  const int rowbase = blockIdx.x * 128 + wr * 64;
  const int pc = blockIdx.y * 2 + wc;          // 64-col panel index

  int t_[4];
#pragma unroll
  for (int tr = 0; tr < 4; ++tr) {
    int t = (rowbase >> 4) + tr;
    t_[tr] = (t < ntiles) ? t : (ntiles - 1);
  }

  const size_t loff = (size_t)l * 8;
  const unsigned short* ah[4];
  const unsigned short* al[4];
#pragma unroll
  for (int tr = 0; tr < 4; ++tr) {
    ah[tr] = Afh + (size_t)t_[tr] * 12 * 512 + loff;
    al[tr] = Afl + (size_t)t_[tr] * 12 * 512 + loff;
  }
  const unsigned short* bh0 = Bfh + (size_t)pc * 4 * ksteps * 512 + loff;
  const unsigned short* bl0 = Bfl + (size_t)pc * 4 * ksteps * 512 + loff;

  f32x4 acc[4][4] = {};
  for (int s = 0; s < ksteps; ++s) {
    bf16x8 Ah[4], Al[4];
#pragma unroll
    for (int tr = 0; tr < 4; ++tr) {
      Ah[tr] = *(const bf16x8*)(ah[tr] + (size_t)s * 512);
      Al[tr] = *(const bf16x8*)(al[tr] + (size_t)s * 512);
    }
#pragma unroll
    for (int nt = 0; nt < 4; ++nt) {
      bf16x8 Bh = *(const bf16x8*)(bh0 + ((size_t)nt * ksteps + s) * 512);
      bf16x8 Bl = *(const bf16x8*)(bl0 + ((size_t)nt * ksteps + s) * 512);
#pragma unroll
      for (int tr = 0; tr < 4; ++tr) {
        acc[tr][nt] = __builtin_amdgcn_mfma_f32_16x16x32_bf16(Ah[tr], Bh, acc[tr][nt], 0, 0, 0);
        acc[tr][nt] = __builtin_amdgcn_mfma_f32_16x16x32_bf16(Ah[tr], Bl, acc[tr][nt], 0, 0, 0);
        acc[tr][nt] = __builtin_amdgcn_mfma_f32_16x16x32_bf16(Al[tr], Bh, acc[tr][nt], 0, 0, 0);
      }
    }
  }

  const int r4 = 4 * (l >> 4), cc = (l & 15);
  const int colp = outcol0 + pc * 64;
#pragma unroll
  for (int tr = 0; tr < 4; ++tr) {
#pragma unroll
    for (int nt = 0; nt < 4; ++nt) {
#pragma unroll
      for (int rr = 0; rr < 4; ++rr) {
        int row = rowbase + tr * 16 + r4 + rr;
        if (row < N) {
          int col = colp + nt * 16 + cc;
          float v = acc[tr][nt][rr];
          C[(size_t)row * ldc + col] = v;
          if (Hb && col < 128) Hb[(size_t)row * D + col] = f2bf(v);
        }
      }
    }
  }
}

// ---------------- host ----------------

extern "C" void kernel_launch(void* const* d_in, const int* in_sizes, int n_in,
                              void* d_out, int out_size, void* d_ws, size_t ws_size,
                              hipStream_t stream) {
  const float* x  = (const float*)d_in[0];
  const int* ei1  = (const int*)d_in[1];
  const int* ei2  = (const int*)d_in[2];
  const float* W0 = (const float*)d_in[3];
  const float* W1 = (const float*)d_in[4];
  const float* Wq = (const float*)d_in[5];
  const float* Wk = (const float*)d_in[6];
  const float* Wv = (const float*)d_in[7];

  const int N  = in_sizes[0] / D;
  const int E1 = in_sizes[1] / 2;
  const int E2 = in_sizes[2] / 2;
  const int* src1 = ei1;
  const int* dst1 = ei1 + E1;
  const int* src2 = ei2;
  const int* dst2 = ei2 + E2;
  const int TILES = (N + 15) / 16;

  float* Cbuf = (float*)d_ws;                       // N x 256
  float* M    = Cbuf + (size_t)N * 256;             // 128x128
  float* Wc   = M + 16384;                          // 384x128
  float* WM   = Wc + 49152;                         // 384x128
  unsigned short* Afh = (unsigned short*)(WM + 49152);   // TILES*12*512
  unsigned short* Afl = Afh + (size_t)TILES * 6144;
  unsigned short* Bfh = Afl + (size_t)TILES * 6144;      // 16*12*512
  unsigned short* Bfl = Bfh + 98304;
  unsigned short* Mfh = Bfl + 98304;                     // 8*4*512
  unsigned short* Mfl = Mfh + 16384;
  unsigned short* Hb  = Mfl + 16384;                     // N x 128 bf16
  int* rp1   = (int*)(Hb + (size_t)N * D);
  int* rp2   = rp1 + (N + 1);
  int* cur1  = rp2 + (N + 1);
  int* cur2  = cur1 + N;
  int* srcs1 = cur2 + N;
  int* srcs2 = srcs1 + E1;

  size_t needed = ((size_t)N * 256 + 16384 + 2 * 49152) * 4ull +
                  ((size_t)2 * TILES * 6144 + 2 * 98304 + 2 * 16384 + (size_t)N * D) * 2ull +
                  ((size_t)2 * (N + 1) + 2ull * N + E1 + E2) * 4ull;
  if (ws_size < needed) return;

  float* out = (float*)d_out;

  // weight precompute
  pre1_k<<<256, 256, 0, stream>>>(Wq, Wk, W0, W1, Wv, M, Wc);
  pre2_k<<<(384 * D + 255) / 256, 256, 0, stream>>>(Wc, M, WM);
  pre3_k<<<(16 * 12 * 512 + 8 * 4 * 512 + 255) / 256, 256, 0, stream>>>(
      Wc, WM, M, Bfh, Bfl, Mfh, Mfl);

  // CSR build
  hipMemsetAsync(cur1, 0, (size_t)N * sizeof(int), stream);
  hipMemsetAsync(cur2, 0, (size_t)N * sizeof(int), stream);
  int ebt = (E1 + E2 + 255) / 256;
  hist2_k<<<ebt, 256, 0, stream>>>(dst1, cur1, E1, dst2, cur2, E2);
  exscan2_k<<<2, 1024, 0, stream>>>(cur1, rp1, cur2, rp2, N);
  fill2_k<<<ebt, 256, 0, stream>>>(src1, dst1, cur1, srcs1, E1,
                                   src2, dst2, cur2, srcs2, E2);

  // A fragments cols 0..127 + Hb = split(x)/bf16(x)
  cvt_k<<<(N * 64 + 255) / 256, 256, 0, stream>>>(x, Afh, Afl, Hb, N * 64);

  const int gx = (N + 127) / 128;
  const int ablocks = (N + 1) / 2;          // 2 nodes per block, 2 waves per node

  // Qt0 = x @ M -> Cbuf cols 128..255 (A steps 0..3, B = Mfrag)
  gemm_mfma<<<dim3(gx, 1), 256, 0, stream>>>(Afh, Afl, 4, Mfh, Mfl,
                                             128, Cbuf, 256, nullptr, N, TILES);

  for (int s = 0; s < 5; ++s) {
    const float* hsrc = (s == 0) ? x : Cbuf;
    const int ldh = (s == 0) ? D : 256;

    agg_k<<<ablocks, 256, 0, stream>>>(hsrc, ldh, Cbuf + 128, Hb,
                                       rp1, srcs1, rp2, srcs2, Afh, Afl, N);

    if (s == 4) {
      gemm_mfma<<<dim3(gx, 1), 256, 0, stream>>>(Afh, Afl, 12, Bfh, Bfl,
                                                 0, out, D, nullptr, N, TILES);
    } else {
      gemm_mfma<<<dim3(gx, 2), 256, 0, stream>>>(Afh, Afl, 12, Bfh, Bfl,
                                                 0, Cbuf, 256, Hb, N, TILES);
    }
  }
}

// Round 8
// 369.829 us; speedup vs baseline: 1.1920x; 1.1920x over previous
//
#include <hip/hip_runtime.h>

#define D 128

typedef __attribute__((ext_vector_type(8))) short bf16x8;
typedef __attribute__((ext_vector_type(4))) float f32x4;

// ---------------- bf16 helpers (RTN-even) ----------------
__device__ __forceinline__ unsigned short f2bf(float f) {
  union { float f; unsigned int u; } c; c.f = f;
  unsigned int u = c.u;
  unsigned int r = (u + 0x7fffu + ((u >> 16) & 1u)) >> 16;
  return (unsigned short)r;
}
__device__ __forceinline__ float bf2f(unsigned short h) {
  return __uint_as_float(((unsigned int)h) << 16);
}
__device__ __forceinline__ float bf_lo(unsigned int w) {
  return __uint_as_float(w << 16);
}
__device__ __forceinline__ float bf_hi(unsigned int w) {
  return __uint_as_float(w & 0xffff0000u);
}
__device__ __forceinline__ void split2(float a, float b, unsigned int& hi, unsigned int& lo) {
  unsigned short ha = f2bf(a), hb = f2bf(b);
  unsigned short la = f2bf(a - bf2f(ha)), lb = f2bf(b - bf2f(hb));
  hi = (unsigned int)ha | ((unsigned int)hb << 16);
  lo = (unsigned int)la | ((unsigned int)lb << 16);
}

// A-fragment layout: Af[((t*12 + s)*64 + (row&15) + 16*((k&31)>>3))*8 + (k&7)]
__device__ __forceinline__ void frag_write(unsigned short* __restrict__ Afh,
                                           unsigned short* __restrict__ Afl,
                                           int t, int r, int k, float a, float b) {
  unsigned int hh, hl;
  split2(a, b, hh, hl);
  int s = k >> 5, ksub = (k & 31) >> 3, e = k & 7;
  size_t addr = ((size_t)(t * 12 + s) * 64 + r + 16 * ksub) * 8 + e;
  *(unsigned int*)&Afh[addr] = hh;
  *(unsigned int*)&Afl[addr] = hl;
}

// ---------------- CSR build ----------------

__global__ void hist2_k(const int* __restrict__ dst1, int* __restrict__ c1, int E1,
                        const int* __restrict__ dst2, int* __restrict__ c2, int E2) {
  int e = blockIdx.x * blockDim.x + threadIdx.x;
  if (e < E1) atomicAdd(&c1[dst1[e]], 1);
  int e2 = e - E1;
  if (e2 >= 0 && e2 < E2) atomicAdd(&c2[dst2[e2]], 1);
}

__device__ void exscan_dev(int* cnt_cursor, int* rp, int n) {
  __shared__ int wsum[16];
  __shared__ int carry_s;
  const int tid = threadIdx.x;
  const int lane = tid & 63, wid = tid >> 6;
  if (tid == 0) carry_s = 0;
  __syncthreads();
  for (int base = 0; base < n; base += 1024) {
    int idx = base + tid;
    int v = (idx < n) ? cnt_cursor[idx] : 0;
    int s = v;
#pragma unroll
    for (int ofs = 1; ofs < 64; ofs <<= 1) {
      int t = __shfl_up(s, ofs);
      if (lane >= ofs) s += t;
    }
    if (lane == 63) wsum[wid] = s;
    __syncthreads();
    if (wid == 0) {
      int ws = (lane < 16) ? wsum[lane] : 0;
#pragma unroll
      for (int ofs = 1; ofs < 16; ofs <<= 1) {
        int t = __shfl_up(ws, ofs);
        if (lane >= ofs) ws += t;
      }
      if (lane < 16) wsum[lane] = ws;
    }
    __syncthreads();
    int pre = (wid > 0) ? wsum[wid - 1] : 0;
    int carry = carry_s;
    int ex = carry + pre + s - v;
    if (idx < n) { rp[idx] = ex; cnt_cursor[idx] = ex; }
    __syncthreads();
    if (tid == 1023) carry_s = carry + wsum[15];
    __syncthreads();
  }
  if (tid == 0) rp[n] = carry_s;
}

__global__ void exscan2_k(int* c1, int* r1, int* c2, int* r2, int n) {
  if (blockIdx.x == 0) exscan_dev(c1, r1, n);
  else exscan_dev(c2, r2, n);
}

__global__ void fill2_k(const int* __restrict__ src1, const int* __restrict__ dst1,
                        int* __restrict__ cur1, int* __restrict__ out1, int E1,
                        const int* __restrict__ src2, const int* __restrict__ dst2,
                        int* __restrict__ cur2, int* __restrict__ out2, int E2) {
  int e = blockIdx.x * blockDim.x + threadIdx.x;
  if (e < E1) {
    int pos = atomicAdd(&cur1[dst1[e]], 1);
    out1[pos] = src1[e];
  }
  int e2 = e - E1;
  if (e2 >= 0 && e2 < E2) {
    int pos = atomicAdd(&cur2[dst2[e2]], 1);
    out2[pos] = src2[e2];
  }
}

// ---------------- weight precompute ----------------
__global__ __launch_bounds__(256) void pre1_k(
    const float* __restrict__ Wq, const float* __restrict__ Wk,
    const float* __restrict__ W0, const float* __restrict__ W1,
    const float* __restrict__ Wv,
    float* __restrict__ M, float* __restrict__ Wc) {
  int bx = blockIdx.x;
  if (bx < 64) {
    int r = bx * 2 + (threadIdx.x >> 7);
    int c = threadIdx.x & 127;
    float acc = 0.f;
    for (int d = 0; d < D; ++d) acc += Wq[r * D + d] * Wk[c * D + d];
    M[r * D + c] = acc;
  } else {
    int idx = (bx - 64) * 256 + threadIdx.x;
    int r = idx >> 7, c = idx & 127;
    float v;
    if (r < 128) v = W0[r * D + c];
    else if (r < 256) v = W1[(r - 128) * D + c];
    else v = -Wv[(r - 256) * D + c];
    Wc[idx] = v;
  }
}

__global__ __launch_bounds__(256) void pre2_k(const float* __restrict__ Wc,
                                              const float* __restrict__ M,
                                              float* __restrict__ WM) {
  int idx = blockIdx.x * blockDim.x + threadIdx.x;
  if (idx >= 384 * D) return;
  int r = idx >> 7, c = idx & 127;
  float acc = 0.f;
  for (int k = 0; k < D; ++k) acc += Wc[r * D + k] * M[k * D + c];
  WM[idx] = acc;
}

// pre3: B fragments. Bf: [ntg 16][s 12][64][8] from [Wc|WM]; Mf: [ntg 8][s 4][64][8] from M.
__global__ __launch_bounds__(256) void pre3_k(
    const float* __restrict__ Wc, const float* __restrict__ WM,
    const float* __restrict__ M,
    unsigned short* __restrict__ Bfh, unsigned short* __restrict__ Bfl,
    unsigned short* __restrict__ Mfh, unsigned short* __restrict__ Mfl) {
  int idx = blockIdx.x * blockDim.x + threadIdx.x;
  if (idx < 16 * 12 * 512) {
    int e = idx & 7, l = (idx >> 3) & 63;
    int s = (idx >> 9) % 12, ntg = idx / (12 * 512);
    int n = ntg * 16 + (l & 15);
    int k = s * 32 + (l >> 4) * 8 + e;
    float v = (n < 128) ? Wc[k * D + n] : WM[k * D + (n - 128)];
    unsigned short h = f2bf(v);
    Bfh[idx] = h;
    Bfl[idx] = f2bf(v - bf2f(h));
  } else {
    int i2 = idx - 16 * 12 * 512;
    if (i2 >= 8 * 4 * 512) return;
    int e = i2 & 7, l = (i2 >> 3) & 63;
    int s = (i2 >> 9) & 3, ntg = i2 / (4 * 512);
    int n = ntg * 16 + (l & 15);
    int k = s * 32 + (l >> 4) * 8 + e;
    float v = M[k * D + n];
    unsigned short h = f2bf(v);
    Mfh[i2] = h;
    Mfl[i2] = f2bf(v - bf2f(h));
  }
}

// x -> A fragments cols 0..127 AND compact bf16 copy Hb
__global__ __launch_bounds__(256) void cvt_k(const float* __restrict__ x,
                                             unsigned short* __restrict__ Afh,
                                             unsigned short* __restrict__ Afl,
                                             unsigned short* __restrict__ Hb, int n) {
  int idx = blockIdx.x * blockDim.x + threadIdx.x;   // n = N*64
  if (idx >= n) return;
  int row = idx >> 6, f = (idx & 63) * 2;
  float2 v = *(const float2*)&x[row * D + f];
  frag_write(Afh, Afl, row >> 4, row & 15, f, v.x, v.y);
  unsigned int p = (unsigned int)f2bf(v.x) | ((unsigned int)f2bf(v.y) << 16);
  *(unsigned int*)&Hb[(size_t)row * D + f] = p;
}

// ---------------- gather/aggregate: one wave per node, bf16 L2-resident gather ----------------
__device__ __forceinline__ float wave_reduce_sum(float v) {
  v += __shfl_xor(v, 32);
  v += __shfl_xor(v, 16);
  v += __shfl_xor(v, 8);
  v += __shfl_xor(v, 4);
  v += __shfl_xor(v, 2);
  v += __shfl_xor(v, 1);
  return v;
}

__global__ __launch_bounds__(256) void agg_k(
    const float* __restrict__ h, int ldh,
    const float* __restrict__ qt,                  // ld 256
    const unsigned short* __restrict__ Hb,         // N x 128 bf16 (gather source)
    const int* __restrict__ rp1, const int* __restrict__ s1,
    const int* __restrict__ rp2, const int* __restrict__ s2,
    unsigned short* __restrict__ Afh, unsigned short* __restrict__ Afl, int N) {
  int gw = (int)((blockIdx.x * blockDim.x + threadIdx.x) >> 6);
  if (gw >= N) return;
  const int i = __builtin_amdgcn_readfirstlane(gw);
  const int l = threadIdx.x & 63;
  const int f = 2 * l;

  float2 hrow = *(const float2*)&h[(size_t)i * ldh + f];
  float2 q = *(const float2*)&qt[(size_t)i * 256 + f];
  float2 a1 = make_float2(0.f, 0.f);
  float2 a2 = make_float2(0.f, 0.f);

  int e = rp1[i], end = rp1[i + 1];
  for (; e + 8 <= end; e += 8) {
    unsigned int w[8];
#pragma unroll
    for (int u = 0; u < 8; ++u) {
      int j = s1[e + u];
      w[u] = *(const unsigned int*)&Hb[(size_t)j * D + f];
    }
#pragma unroll
    for (int u = 0; u < 8; ++u) { a1.x += bf_lo(w[u]); a1.y += bf_hi(w[u]); }
  }
  for (; e < end; ++e) {
    int j = s1[e];
    unsigned int w = *(const unsigned int*)&Hb[(size_t)j * D + f];
    a1.x += bf_lo(w); a1.y += bf_hi(w);
  }

  e = rp2[i]; end = rp2[i + 1];
  for (; e + 4 <= end; e += 4) {
    float2 v[4]; float p[4];
#pragma unroll
    for (int u = 0; u < 4; ++u) {
      int j = s2[e + u];
      unsigned int w = *(const unsigned int*)&Hb[(size_t)j * D + f];
      v[u] = make_float2(bf_lo(w), bf_hi(w));
    }
#pragma unroll
    for (int u = 0; u < 4; ++u) p[u] = q.x * v[u].x + q.y * v[u].y;
#pragma unroll
    for (int ofs = 32; ofs >= 1; ofs >>= 1) {
#pragma unroll
      for (int u = 0; u < 4; ++u) p[u] += __shfl_xor(p[u], ofs);
    }
#pragma unroll
    for (int u = 0; u < 4; ++u) {
      a2.x += p[u] * v[u].x; a2.y += p[u] * v[u].y;
    }
  }
  for (; e < end; ++e) {
    int j = s2[e];
    unsigned int w = *(const unsigned int*)&Hb[(size_t)j * D + f];
    float2 v = make_float2(bf_lo(w), bf_hi(w));
    float p = wave_reduce_sum(q.x * v.x + q.y * v.y);
    a2.x += p * v.x; a2.y += p * v.y;
  }

  const int t = i >> 4, r = i & 15;
  frag_write(Afh, Afl, t, r, f, hrow.x, hrow.y);
  frag_write(Afh, Afl, t, r, 128 + f, a1.x, a1.y);
  frag_write(Afh, Afl, t, r, 256 + f, a2.x, a2.y);
}

// ---------------- fragment-layout split-bf16 MFMA GEMM (occupancy-packed) ----------------
// Block 256 = 4 waves (2 row x 2 col). Block tile: 64 rows x 64 cols.
// Wave: 32 rows (2 tiles) x 32 cols (2 ntg). Per k-step: 12 MFMA : 8 loads, acc 16 VGPR.
// Grid: x = ceil(N/64), y = outcols/64.
__global__ __launch_bounds__(256) void gemm_mfma(
    const unsigned short* __restrict__ Afh, const unsigned short* __restrict__ Afl,
    int ksteps,
    const unsigned short* __restrict__ Bfh, const unsigned short* __restrict__ Bfl,
    int outcol0, float* __restrict__ C, int ldc,
    unsigned short* __restrict__ Hb,            // optional bf16 copy (cols<128)
    int N, int ntiles) {
  const int w = threadIdx.x >> 6, l = threadIdx.x & 63;
  const int wr = w & 1, wc = w >> 1;
  const int rowbase = blockIdx.x * 64 + wr * 32;
  const int ntg0 = blockIdx.y * 4 + wc * 2;     // first 16-col group of this wave

  int t_[2];
#pragma unroll
  for (int tr = 0; tr < 2; ++tr) {
    int t = (rowbase >> 4) + tr;
    t_[tr] = (t < ntiles) ? t : (ntiles - 1);
  }

  const size_t loff = (size_t)l * 8;
  const unsigned short* ah[2];
  const unsigned short* al[2];
#pragma unroll
  for (int tr = 0; tr < 2; ++tr) {
    ah[tr] = Afh + (size_t)t_[tr] * 12 * 512 + loff;
    al[tr] = Afl + (size_t)t_[tr] * 12 * 512 + loff;
  }
  const unsigned short* bh[2];
  const unsigned short* bl[2];
#pragma unroll
  for (int nt = 0; nt < 2; ++nt) {
    bh[nt] = Bfh + (size_t)(ntg0 + nt) * ksteps * 512 + loff;
    bl[nt] = Bfl + (size_t)(ntg0 + nt) * ksteps * 512 + loff;
  }

  f32x4 acc[2][2] = {};
  for (int s = 0; s < ksteps; ++s) {
    bf16x8 Ah[2], Al[2], Bh[2], Bl[2];
#pragma unroll
    for (int tr = 0; tr < 2; ++tr) {
      Ah[tr] = *(const bf16x8*)(ah[tr] + (size_t)s * 512);
      Al[tr] = *(const bf16x8*)(al[tr] + (size_t)s * 512);
    }
#pragma unroll
    for (int nt = 0; nt < 2; ++nt) {
      Bh[nt] = *(const bf16x8*)(bh[nt] + (size_t)s * 512);
      Bl[nt] = *(const bf16x8*)(bl[nt] + (size_t)s * 512);
    }
#pragma unroll
    for (int nt = 0; nt < 2; ++nt) {
#pragma unroll
      for (int tr = 0; tr < 2; ++tr) {
        acc[tr][nt] = __builtin_amdgcn_mfma_f32_16x16x32_bf16(Ah[tr], Bh[nt], acc[tr][nt], 0, 0, 0);
        acc[tr][nt] = __builtin_amdgcn_mfma_f32_16x16x32_bf16(Ah[tr], Bl[nt], acc[tr][nt], 0, 0, 0);
        acc[tr][nt] = __builtin_amdgcn_mfma_f32_16x16x32_bf16(Al[tr], Bh[nt], acc[tr][nt], 0, 0, 0);
      }
    }
  }

  const int r4 = 4 * (l >> 4), cc = (l & 15);
#pragma unroll
  for (int tr = 0; tr < 2; ++tr) {
#pragma unroll
    for (int nt = 0; nt < 2; ++nt) {
      int col = outcol0 + (ntg0 + nt) * 16 + cc;
#pragma unroll
      for (int rr = 0; rr < 4; ++rr) {
        int row = rowbase + tr * 16 + r4 + rr;
        if (row < N) {
          float v = acc[tr][nt][rr];
          C[(size_t)row * ldc + col] = v;
          if (Hb && col < 128) Hb[(size_t)row * D + col] = f2bf(v);
        }
      }
    }
  }
}

// ---------------- host ----------------

extern "C" void kernel_launch(void* const* d_in, const int* in_sizes, int n_in,
                              void* d_out, int out_size, void* d_ws, size_t ws_size,
                              hipStream_t stream) {
  const float* x  = (const float*)d_in[0];
  const int* ei1  = (const int*)d_in[1];
  const int* ei2  = (const int*)d_in[2];
  const float* W0 = (const float*)d_in[3];
  const float* W1 = (const float*)d_in[4];
  const float* Wq = (const float*)d_in[5];
  const float* Wk = (const float*)d_in[6];
  const float* Wv = (const float*)d_in[7];

  const int N  = in_sizes[0] / D;
  const int E1 = in_sizes[1] / 2;
  const int E2 = in_sizes[2] / 2;
  const int* src1 = ei1;
  const int* dst1 = ei1 + E1;
  const int* src2 = ei2;
  const int* dst2 = ei2 + E2;
  const int TILES = (N + 15) / 16;

  float* Cbuf = (float*)d_ws;                       // N x 256
  float* M    = Cbuf + (size_t)N * 256;             // 128x128
  float* Wc   = M + 16384;                          // 384x128
  float* WM   = Wc + 49152;                         // 384x128
  unsigned short* Afh = (unsigned short*)(WM + 49152);   // TILES*12*512
  unsigned short* Afl = Afh + (size_t)TILES * 6144;
  unsigned short* Bfh = Afl + (size_t)TILES * 6144;      // 16*12*512
  unsigned short* Bfl = Bfh + 98304;
  unsigned short* Mfh = Bfl + 98304;                     // 8*4*512
  unsigned short* Mfl = Mfh + 16384;
  unsigned short* Hb  = Mfl + 16384;                     // N x 128 bf16
  int* rp1   = (int*)(Hb + (size_t)N * D);
  int* rp2   = rp1 + (N + 1);
  int* cur1  = rp2 + (N + 1);
  int* cur2  = cur1 + N;
  int* srcs1 = cur2 + N;
  int* srcs2 = srcs1 + E1;

  size_t needed = ((size_t)N * 256 + 16384 + 2 * 49152) * 4ull +
                  ((size_t)2 * TILES * 6144 + 2 * 98304 + 2 * 16384 + (size_t)N * D) * 2ull +
                  ((size_t)2 * (N + 1) + 2ull * N + E1 + E2) * 4ull;
  if (ws_size < needed) return;

  float* out = (float*)d_out;

  // weight precompute
  pre1_k<<<256, 256, 0, stream>>>(Wq, Wk, W0, W1, Wv, M, Wc);
  pre2_k<<<(384 * D + 255) / 256, 256, 0, stream>>>(Wc, M, WM);
  pre3_k<<<(16 * 12 * 512 + 8 * 4 * 512 + 255) / 256, 256, 0, stream>>>(
      Wc, WM, M, Bfh, Bfl, Mfh, Mfl);

  // CSR build (cur1,cur2 contiguous -> single memset)
  hipMemsetAsync(cur1, 0, (size_t)2 * N * sizeof(int), stream);
  int ebt = (E1 + E2 + 255) / 256;
  hist2_k<<<ebt, 256, 0, stream>>>(dst1, cur1, E1, dst2, cur2, E2);
  exscan2_k<<<2, 1024, 0, stream>>>(cur1, rp1, cur2, rp2, N);
  fill2_k<<<ebt, 256, 0, stream>>>(src1, dst1, cur1, srcs1, E1,
                                   src2, dst2, cur2, srcs2, E2);

  // A fragments cols 0..127 + Hb = split(x)/bf16(x)
  cvt_k<<<(N * 64 + 255) / 256, 256, 0, stream>>>(x, Afh, Afl, Hb, N * 64);

  const int gx = (N + 63) / 64;
  const int ablocks = (N * 64 + 255) / 256;

  // Qt0 = x @ M -> Cbuf cols 128..255 (A steps 0..3, B = Mfrag; 128 outcols -> y=2)
  gemm_mfma<<<dim3(gx, 2), 256, 0, stream>>>(Afh, Afl, 4, Mfh, Mfl,
                                             128, Cbuf, 256, nullptr, N, TILES);

  for (int s = 0; s < 5; ++s) {
    const float* hsrc = (s == 0) ? x : Cbuf;
    const int ldh = (s == 0) ? D : 256;

    agg_k<<<ablocks, 256, 0, stream>>>(hsrc, ldh, Cbuf + 128, Hb,
                                       rp1, srcs1, rp2, srcs2, Afh, Afl, N);

    if (s == 4) {
      gemm_mfma<<<dim3(gx, 2), 256, 0, stream>>>(Afh, Afl, 12, Bfh, Bfl,
                                                 0, out, D, nullptr, N, TILES);
    } else {
      gemm_mfma<<<dim3(gx, 4), 256, 0, stream>>>(Afh, Afl, 12, Bfh, Bfl,
                                                 0, Cbuf, 256, Hb, N, TILES);
    }
  }
}

// Round 9
// 350.071 us; speedup vs baseline: 1.2593x; 1.0564x over previous
//
#include <hip/hip_runtime.h>

#define D 128

typedef __attribute__((ext_vector_type(8))) short bf16x8;
typedef __attribute__((ext_vector_type(4))) float f32x4;

// ---------------- bf16 helpers (RTN-even) ----------------
__device__ __forceinline__ unsigned short f2bf(float f) {
  union { float f; unsigned int u; } c; c.f = f;
  unsigned int u = c.u;
  unsigned int r = (u + 0x7fffu + ((u >> 16) & 1u)) >> 16;
  return (unsigned short)r;
}
__device__ __forceinline__ float bf2f(unsigned short h) {
  return __uint_as_float(((unsigned int)h) << 16);
}
__device__ __forceinline__ float bf_lo(unsigned int w) {
  return __uint_as_float(w << 16);
}
__device__ __forceinline__ float bf_hi(unsigned int w) {
  return __uint_as_float(w & 0xffff0000u);
}
__device__ __forceinline__ void split2(float a, float b, unsigned int& hi, unsigned int& lo) {
  unsigned short ha = f2bf(a), hb = f2bf(b);
  unsigned short la = f2bf(a - bf2f(ha)), lb = f2bf(b - bf2f(hb));
  hi = (unsigned int)ha | ((unsigned int)hb << 16);
  lo = (unsigned int)la | ((unsigned int)lb << 16);
}

// A-fragment layout: Af[((t*12 + s)*64 + (row&15) + 16*((k&31)>>3))*8 + (k&7)]
__device__ __forceinline__ void frag_write(unsigned short* __restrict__ Afh,
                                           unsigned short* __restrict__ Afl,
                                           int t, int r, int k, float a, float b) {
  unsigned int hh, hl;
  split2(a, b, hh, hl);
  int s = k >> 5, ksub = (k & 31) >> 3, e = k & 7;
  size_t addr = ((size_t)(t * 12 + s) * 64 + r + 16 * ksub) * 8 + e;
  *(unsigned int*)&Afh[addr] = hh;
  *(unsigned int*)&Afl[addr] = hl;
}

// ---------------- CSR build ----------------

__global__ void hist2_k(const int* __restrict__ dst1, int* __restrict__ c1, int E1,
                        const int* __restrict__ dst2, int* __restrict__ c2, int E2) {
  int e = blockIdx.x * blockDim.x + threadIdx.x;
  if (e < E1) atomicAdd(&c1[dst1[e]], 1);
  int e2 = e - E1;
  if (e2 >= 0 && e2 < E2) atomicAdd(&c2[dst2[e2]], 1);
}

__device__ void exscan_dev(int* cnt_cursor, int* rp, int n) {
  __shared__ int wsum[16];
  __shared__ int carry_s;
  const int tid = threadIdx.x;
  const int lane = tid & 63, wid = tid >> 6;
  if (tid == 0) carry_s = 0;
  __syncthreads();
  for (int base = 0; base < n; base += 1024) {
    int idx = base + tid;
    int v = (idx < n) ? cnt_cursor[idx] : 0;
    int s = v;
#pragma unroll
    for (int ofs = 1; ofs < 64; ofs <<= 1) {
      int t = __shfl_up(s, ofs);
      if (lane >= ofs) s += t;
    }
    if (lane == 63) wsum[wid] = s;
    __syncthreads();
    if (wid == 0) {
      int ws = (lane < 16) ? wsum[lane] : 0;
#pragma unroll
      for (int ofs = 1; ofs < 16; ofs <<= 1) {
        int t = __shfl_up(ws, ofs);
        if (lane >= ofs) ws += t;
      }
      if (lane < 16) wsum[lane] = ws;
    }
    __syncthreads();
    int pre = (wid > 0) ? wsum[wid - 1] : 0;
    int carry = carry_s;
    int ex = carry + pre + s - v;
    if (idx < n) { rp[idx] = ex; cnt_cursor[idx] = ex; }
    __syncthreads();
    if (tid == 1023) carry_s = carry + wsum[15];
    __syncthreads();
  }
  if (tid == 0) rp[n] = carry_s;
}

__global__ void exscan2_k(int* c1, int* r1, int* c2, int* r2, int n) {
  if (blockIdx.x == 0) exscan_dev(c1, r1, n);
  else exscan_dev(c2, r2, n);
}

__global__ void fill2_k(const int* __restrict__ src1, const int* __restrict__ dst1,
                        int* __restrict__ cur1, int* __restrict__ out1, int E1,
                        const int* __restrict__ src2, const int* __restrict__ dst2,
                        int* __restrict__ cur2, int* __restrict__ out2, int E2) {
  int e = blockIdx.x * blockDim.x + threadIdx.x;
  if (e < E1) {
    int pos = atomicAdd(&cur1[dst1[e]], 1);
    out1[pos] = src1[e];
  }
  int e2 = e - E1;
  if (e2 >= 0 && e2 < E2) {
    int pos = atomicAdd(&cur2[dst2[e2]], 1);
    out2[pos] = src2[e2];
  }
}

// ---------------- weight precompute ----------------
__global__ __launch_bounds__(256) void pre1_k(
    const float* __restrict__ Wq, const float* __restrict__ Wk,
    const float* __restrict__ W0, const float* __restrict__ W1,
    const float* __restrict__ Wv,
    float* __restrict__ M, float* __restrict__ Wc) {
  int bx = blockIdx.x;
  if (bx < 64) {
    int r = bx * 2 + (threadIdx.x >> 7);
    int c = threadIdx.x & 127;
    float acc = 0.f;
    for (int d = 0; d < D; ++d) acc += Wq[r * D + d] * Wk[c * D + d];
    M[r * D + c] = acc;
  } else {
    int idx = (bx - 64) * 256 + threadIdx.x;
    int r = idx >> 7, c = idx & 127;
    float v;
    if (r < 128) v = W0[r * D + c];
    else if (r < 256) v = W1[(r - 128) * D + c];
    else v = -Wv[(r - 256) * D + c];
    Wc[idx] = v;
  }
}

__global__ __launch_bounds__(256) void pre2_k(const float* __restrict__ Wc,
                                              const float* __restrict__ M,
                                              float* __restrict__ WM) {
  int idx = blockIdx.x * blockDim.x + threadIdx.x;
  if (idx >= 384 * D) return;
  int r = idx >> 7, c = idx & 127;
  float acc = 0.f;
  for (int k = 0; k < D; ++k) acc += Wc[r * D + k] * M[k * D + c];
  WM[idx] = acc;
}

// pre3: B fragments. Bf: [ntg 16][s 12][64][8] from [Wc|WM]; Mf: [ntg 8][s 4][64][8] from M.
__global__ __launch_bounds__(256) void pre3_k(
    const float* __restrict__ Wc, const float* __restrict__ WM,
    const float* __restrict__ M,
    unsigned short* __restrict__ Bfh, unsigned short* __restrict__ Bfl,
    unsigned short* __restrict__ Mfh, unsigned short* __restrict__ Mfl) {
  int idx = blockIdx.x * blockDim.x + threadIdx.x;
  if (idx < 16 * 12 * 512) {
    int e = idx & 7, l = (idx >> 3) & 63;
    int s = (idx >> 9) % 12, ntg = idx / (12 * 512);
    int n = ntg * 16 + (l & 15);
    int k = s * 32 + (l >> 4) * 8 + e;
    float v = (n < 128) ? Wc[k * D + n] : WM[k * D + (n - 128)];
    unsigned short h = f2bf(v);
    Bfh[idx] = h;
    Bfl[idx] = f2bf(v - bf2f(h));
  } else {
    int i2 = idx - 16 * 12 * 512;
    if (i2 >= 8 * 4 * 512) return;
    int e = i2 & 7, l = (i2 >> 3) & 63;
    int s = (i2 >> 9) & 3, ntg = i2 / (4 * 512);
    int n = ntg * 16 + (l & 15);
    int k = s * 32 + (l >> 4) * 8 + e;
    float v = M[k * D + n];
    unsigned short h = f2bf(v);
    Mfh[i2] = h;
    Mfl[i2] = f2bf(v - bf2f(h));
  }
}

// x -> A fragments cols 0..127 AND compact bf16 copy Hb
__global__ __launch_bounds__(256) void cvt_k(const float* __restrict__ x,
                                             unsigned short* __restrict__ Afh,
                                             unsigned short* __restrict__ Afl,
                                             unsigned short* __restrict__ Hb, int n) {
  int idx = blockIdx.x * blockDim.x + threadIdx.x;   // n = N*64
  if (idx >= n) return;
  int row = idx >> 6, f = (idx & 63) * 2;
  float2 v = *(const float2*)&x[row * D + f];
  frag_write(Afh, Afl, row >> 4, row & 15, f, v.x, v.y);
  unsigned int p = (unsigned int)f2bf(v.x) | ((unsigned int)f2bf(v.y) << 16);
  *(unsigned int*)&Hb[(size_t)row * D + f] = p;
}

// ---------------- gather/aggregate v2: 1 wave/node, 4 groups x 16 lanes ----------------
// lane = 16g+m. Group handles one edge per batch; lane loads 8 bf16 cols (16B).
// Per 8-edge batch: 2 index loads + 2 gathers (16B/lane).
__global__ __launch_bounds__(256) void agg_k(
    const float* __restrict__ h, int ldh,
    const float* __restrict__ qt,                  // ld 256
    const unsigned short* __restrict__ Hb,         // N x 128 bf16 (gather source)
    const int* __restrict__ rp1, const int* __restrict__ s1,
    const int* __restrict__ rp2, const int* __restrict__ s2,
    unsigned short* __restrict__ Afh, unsigned short* __restrict__ Afl, int N) {
  int gw = (int)((blockIdx.x * blockDim.x + threadIdx.x) >> 6);
  if (gw >= N) return;
  const int i = __builtin_amdgcn_readfirstlane(gw);
  const int l = threadIdx.x & 63;
  const int m = l & 15, g = l >> 4;
  const int c0 = m * 8;

  float q[8];
  *(float4*)&q[0] = *(const float4*)&qt[(size_t)i * 256 + c0];
  *(float4*)&q[4] = *(const float4*)&qt[(size_t)i * 256 + c0 + 4];

  float a1[8] = {0.f, 0.f, 0.f, 0.f, 0.f, 0.f, 0.f, 0.f};
  float a2[8] = {0.f, 0.f, 0.f, 0.f, 0.f, 0.f, 0.f, 0.f};

  // ---- CSR1: neighbor sum ----
  {
    const int lo = rp1[i], end = rp1[i + 1];
    for (int e = lo; e < end; e += 8) {
      int e0 = e + g, e1 = e + 4 + g;
      bool v0 = e0 < end, v1 = e1 < end;
      int j0 = v0 ? s1[e0] : 0;
      int j1 = v1 ? s1[e1] : 0;
      uint4 w0 = *(const uint4*)&Hb[(size_t)j0 * D + c0];
      uint4 w1 = *(const uint4*)&Hb[(size_t)j1 * D + c0];
      if (!v0) w0 = make_uint4(0u, 0u, 0u, 0u);
      if (!v1) w1 = make_uint4(0u, 0u, 0u, 0u);
      a1[0] += bf_lo(w0.x) + bf_lo(w1.x); a1[1] += bf_hi(w0.x) + bf_hi(w1.x);
      a1[2] += bf_lo(w0.y) + bf_lo(w1.y); a1[3] += bf_hi(w0.y) + bf_hi(w1.y);
      a1[4] += bf_lo(w0.z) + bf_lo(w1.z); a1[5] += bf_hi(w0.z) + bf_hi(w1.z);
      a1[6] += bf_lo(w0.w) + bf_lo(w1.w); a1[7] += bf_hi(w0.w) + bf_hi(w1.w);
    }
  }

  // ---- CSR2: attention aggregate ----
  {
    const int lo = rp2[i], end = rp2[i + 1];
    for (int e = lo; e < end; e += 8) {
      int e0 = e + g, e1 = e + 4 + g;
      bool v0 = e0 < end, v1 = e1 < end;
      int j0 = v0 ? s2[e0] : 0;
      int j1 = v1 ? s2[e1] : 0;
      uint4 w0 = *(const uint4*)&Hb[(size_t)j0 * D + c0];
      uint4 w1 = *(const uint4*)&Hb[(size_t)j1 * D + c0];
      if (!v0) w0 = make_uint4(0u, 0u, 0u, 0u);
      if (!v1) w1 = make_uint4(0u, 0u, 0u, 0u);
      float f0[8], f1[8];
      f0[0] = bf_lo(w0.x); f0[1] = bf_hi(w0.x); f0[2] = bf_lo(w0.y); f0[3] = bf_hi(w0.y);
      f0[4] = bf_lo(w0.z); f0[5] = bf_hi(w0.z); f0[6] = bf_lo(w0.w); f0[7] = bf_hi(w0.w);
      f1[0] = bf_lo(w1.x); f1[1] = bf_hi(w1.x); f1[2] = bf_lo(w1.y); f1[3] = bf_hi(w1.y);
      f1[4] = bf_lo(w1.z); f1[5] = bf_hi(w1.z); f1[6] = bf_lo(w1.w); f1[7] = bf_hi(w1.w);
      float p0 = q[0] * f0[0] + q[1] * f0[1] + q[2] * f0[2] + q[3] * f0[3] +
                 q[4] * f0[4] + q[5] * f0[5] + q[6] * f0[6] + q[7] * f0[7];
      float p1 = q[0] * f1[0] + q[1] * f1[1] + q[2] * f1[2] + q[3] * f1[3] +
                 q[4] * f1[4] + q[5] * f1[5] + q[6] * f1[6] + q[7] * f1[7];
#pragma unroll
      for (int ofs = 1; ofs < 16; ofs <<= 1) {
        p0 += __shfl_xor(p0, ofs);
        p1 += __shfl_xor(p1, ofs);
      }
#pragma unroll
      for (int t = 0; t < 8; ++t) a2[t] += p0 * f0[t] + p1 * f1[t];
    }
  }

  // ---- cross-group combine ----
#pragma unroll
  for (int t = 0; t < 8; ++t) {
    a1[t] += __shfl_xor(a1[t], 16); a1[t] += __shfl_xor(a1[t], 32);
    a2[t] += __shfl_xor(a2[t], 16); a2[t] += __shfl_xor(a2[t], 32);
  }

  // ---- fragment writes: g=0 -> h row, g=1 -> a1, g=2 -> a2 ----
  if (g < 3) {
    float vals[8];
    if (g == 0) {
      *(float4*)&vals[0] = *(const float4*)&h[(size_t)i * ldh + c0];
      *(float4*)&vals[4] = *(const float4*)&h[(size_t)i * ldh + c0 + 4];
    } else if (g == 1) {
#pragma unroll
      for (int t = 0; t < 8; ++t) vals[t] = a1[t];
    } else {
#pragma unroll
      for (int t = 0; t < 8; ++t) vals[t] = a2[t];
    }
    uint4 hiw, low;
    split2(vals[0], vals[1], hiw.x, low.x);
    split2(vals[2], vals[3], hiw.y, low.y);
    split2(vals[4], vals[5], hiw.z, low.z);
    split2(vals[6], vals[7], hiw.w, low.w);
    size_t base = (((size_t)(i >> 4) * 12 + g * 4 + (m >> 2)) * 64 +
                   (i & 15) + 16 * (m & 3)) * 8;
    *(uint4*)&Afh[base] = hiw;
    *(uint4*)&Afl[base] = low;
  }
}

// ---------------- fragment-layout split-bf16 MFMA GEMM (occupancy-packed) ----------------
// Block 256 = 4 waves (2 row x 2 col). Block tile: 64 rows x 64 cols.
// Wave: 32 rows (2 tiles) x 32 cols (2 ntg). Per k-step: 12 MFMA : 8 loads.
__global__ __launch_bounds__(256) void gemm_mfma(
    const unsigned short* __restrict__ Afh, const unsigned short* __restrict__ Afl,
    int ksteps,
    const unsigned short* __restrict__ Bfh, const unsigned short* __restrict__ Bfl,
    int outcol0, float* __restrict__ C, int ldc,
    unsigned short* __restrict__ Hb,            // optional bf16 copy (cols<128)
    int N, int ntiles) {
  const int w = threadIdx.x >> 6, l = threadIdx.x & 63;
  const int wr = w & 1, wc = w >> 1;
  const int rowbase = blockIdx.x * 64 + wr * 32;
  const int ntg0 = blockIdx.y * 4 + wc * 2;     // first 16-col group of this wave

  int t_[2];
#pragma unroll
  for (int tr = 0; tr < 2; ++tr) {
    int t = (rowbase >> 4) + tr;
    t_[tr] = (t < ntiles) ? t : (ntiles - 1);
  }

  const size_t loff = (size_t)l * 8;
  const unsigned short* ah[2];
  const unsigned short* al[2];
#pragma unroll
  for (int tr = 0; tr < 2; ++tr) {
    ah[tr] = Afh + (size_t)t_[tr] * 12 * 512 + loff;
    al[tr] = Afl + (size_t)t_[tr] * 12 * 512 + loff;
  }
  const unsigned short* bh[2];
  const unsigned short* bl[2];
#pragma unroll
  for (int nt = 0; nt < 2; ++nt) {
    bh[nt] = Bfh + (size_t)(ntg0 + nt) * ksteps * 512 + loff;
    bl[nt] = Bfl + (size_t)(ntg0 + nt) * ksteps * 512 + loff;
  }

  f32x4 acc[2][2] = {};
  for (int s = 0; s < ksteps; ++s) {
    bf16x8 Ah[2], Al[2], Bh[2], Bl[2];
#pragma unroll
    for (int tr = 0; tr < 2; ++tr) {
      Ah[tr] = *(const bf16x8*)(ah[tr] + (size_t)s * 512);
      Al[tr] = *(const bf16x8*)(al[tr] + (size_t)s * 512);
    }
#pragma unroll
    for (int nt = 0; nt < 2; ++nt) {
      Bh[nt] = *(const bf16x8*)(bh[nt] + (size_t)s * 512);
      Bl[nt] = *(const bf16x8*)(bl[nt] + (size_t)s * 512);
    }
#pragma unroll
    for (int nt = 0; nt < 2; ++nt) {
#pragma unroll
      for (int tr = 0; tr < 2; ++tr) {
        acc[tr][nt] = __builtin_amdgcn_mfma_f32_16x16x32_bf16(Ah[tr], Bh[nt], acc[tr][nt], 0, 0, 0);
        acc[tr][nt] = __builtin_amdgcn_mfma_f32_16x16x32_bf16(Ah[tr], Bl[nt], acc[tr][nt], 0, 0, 0);
        acc[tr][nt] = __builtin_amdgcn_mfma_f32_16x16x32_bf16(Al[tr], Bh[nt], acc[tr][nt], 0, 0, 0);
      }
    }
  }

  const int r4 = 4 * (l >> 4), cc = (l & 15);
#pragma unroll
  for (int tr = 0; tr < 2; ++tr) {
#pragma unroll
    for (int nt = 0; nt < 2; ++nt) {
      int col = outcol0 + (ntg0 + nt) * 16 + cc;
#pragma unroll
      for (int rr = 0; rr < 4; ++rr) {
        int row = rowbase + tr * 16 + r4 + rr;
        if (row < N) {
          float v = acc[tr][nt][rr];
          C[(size_t)row * ldc + col] = v;
          if (Hb && col < 128) Hb[(size_t)row * D + col] = f2bf(v);
        }
      }
    }
  }
}

// ---------------- host ----------------

extern "C" void kernel_launch(void* const* d_in, const int* in_sizes, int n_in,
                              void* d_out, int out_size, void* d_ws, size_t ws_size,
                              hipStream_t stream) {
  const float* x  = (const float*)d_in[0];
  const int* ei1  = (const int*)d_in[1];
  const int* ei2  = (const int*)d_in[2];
  const float* W0 = (const float*)d_in[3];
  const float* W1 = (const float*)d_in[4];
  const float* Wq = (const float*)d_in[5];
  const float* Wk = (const float*)d_in[6];
  const float* Wv = (const float*)d_in[7];

  const int N  = in_sizes[0] / D;
  const int E1 = in_sizes[1] / 2;
  const int E2 = in_sizes[2] / 2;
  const int* src1 = ei1;
  const int* dst1 = ei1 + E1;
  const int* src2 = ei2;
  const int* dst2 = ei2 + E2;
  const int TILES = (N + 15) / 16;

  float* Cbuf = (float*)d_ws;                       // N x 256
  float* M    = Cbuf + (size_t)N * 256;             // 128x128
  float* Wc   = M + 16384;                          // 384x128
  float* WM   = Wc + 49152;                         // 384x128
  unsigned short* Afh = (unsigned short*)(WM + 49152);   // TILES*12*512
  unsigned short* Afl = Afh + (size_t)TILES * 6144;
  unsigned short* Bfh = Afl + (size_t)TILES * 6144;      // 16*12*512
  unsigned short* Bfl = Bfh + 98304;
  unsigned short* Mfh = Bfl + 98304;                     // 8*4*512
  unsigned short* Mfl = Mfh + 16384;
  unsigned short* Hb  = Mfl + 16384;                     // N x 128 bf16
  int* rp1   = (int*)(Hb + (size_t)N * D);
  int* rp2   = rp1 + (N + 1);
  int* cur1  = rp2 + (N + 1);
  int* cur2  = cur1 + N;
  int* srcs1 = cur2 + N;
  int* srcs2 = srcs1 + E1;

  size_t needed = ((size_t)N * 256 + 16384 + 2 * 49152) * 4ull +
                  ((size_t)2 * TILES * 6144 + 2 * 98304 + 2 * 16384 + (size_t)N * D) * 2ull +
                  ((size_t)2 * (N + 1) + 2ull * N + E1 + E2) * 4ull;
  if (ws_size < needed) return;

  float* out = (float*)d_out;

  // weight precompute
  pre1_k<<<256, 256, 0, stream>>>(Wq, Wk, W0, W1, Wv, M, Wc);
  pre2_k<<<(384 * D + 255) / 256, 256, 0, stream>>>(Wc, M, WM);
  pre3_k<<<(16 * 12 * 512 + 8 * 4 * 512 + 255) / 256, 256, 0, stream>>>(
      Wc, WM, M, Bfh, Bfl, Mfh, Mfl);

  // CSR build (cur1,cur2 contiguous -> single memset)
  hipMemsetAsync(cur1, 0, (size_t)2 * N * sizeof(int), stream);
  int ebt = (E1 + E2 + 255) / 256;
  hist2_k<<<ebt, 256, 0, stream>>>(dst1, cur1, E1, dst2, cur2, E2);
  exscan2_k<<<2, 1024, 0, stream>>>(cur1, rp1, cur2, rp2, N);
  fill2_k<<<ebt, 256, 0, stream>>>(src1, dst1, cur1, srcs1, E1,
                                   src2, dst2, cur2, srcs2, E2);

  // A fragments cols 0..127 + Hb = split(x)/bf16(x)
  cvt_k<<<(N * 64 + 255) / 256, 256, 0, stream>>>(x, Afh, Afl, Hb, N * 64);

  const int gx = (N + 63) / 64;
  const int ablocks = (N * 64 + 255) / 256;

  // Qt0 = x @ M -> Cbuf cols 128..255 (A steps 0..3, B = Mfrag; 128 outcols -> y=2)
  gemm_mfma<<<dim3(gx, 2), 256, 0, stream>>>(Afh, Afl, 4, Mfh, Mfl,
                                             128, Cbuf, 256, nullptr, N, TILES);

  for (int s = 0; s < 5; ++s) {
    const float* hsrc = (s == 0) ? x : Cbuf;
    const int ldh = (s == 0) ? D : 256;

    agg_k<<<ablocks, 256, 0, stream>>>(hsrc, ldh, Cbuf + 128, Hb,
                                       rp1, srcs1, rp2, srcs2, Afh, Afl, N);

    if (s == 4) {
      gemm_mfma<<<dim3(gx, 2), 256, 0, stream>>>(Afh, Afl, 12, Bfh, Bfl,
                                                 0, out, D, nullptr, N, TILES);
    } else {
      gemm_mfma<<<dim3(gx, 4), 256, 0, stream>>>(Afh, Afl, 12, Bfh, Bfl,
                                                 0, Cbuf, 256, Hb, N, TILES);
    }
  }
}